// Round 5
// baseline (3920.961 us; speedup 1.0000x reference)
//
#include <hip/hip_runtime.h>
#include <hip/hip_bf16.h>

// LiftSplatShoot voxel pooling, B=1, N=6, D=41, H=64, W=176, C=32, grid 200x200x1.
// nprime = 2,770,944 points. rank = ix*200 + iy (nx2=1, B=1).
// out[c*40000 + ix*200 + iy] = sum over points in voxel (ix,iy) of x[p][c].
// Inputs float32; OUTPUT float32 (the reference returns f32 — the "bf16" in the
// test's error label is a hardcoded f-string, not the actual read-back dtype).
// R4's deterministic absmax=65.0 across atomic flavors == signature of writing
// packed bf16 into an f32-read buffer. R5: write f32.

#define NVOX 40000
#define NCH  32

__device__ __forceinline__ void atomic_add_agent(float* p, float v) {
    __hip_atomic_fetch_add(p, v, __ATOMIC_RELAXED, __HIP_MEMORY_SCOPE_AGENT);
}

__global__ void __launch_bounds__(256)
lss_scatter(const float* __restrict__ geom,
            const float* __restrict__ x,
            float* __restrict__ acc, int nprime, int c0, int cg) {
    int p = blockIdx.x * blockDim.x + threadIdx.x;
    if (p >= nprime) return;

    // Exact reference arithmetic: t = (g - (bx - dx/2)) / dx, trunc toward zero.
    float gx = geom[3 * (size_t)p + 0];
    float gy = geom[3 * (size_t)p + 1];
    float gz = geom[3 * (size_t)p + 2];

    float tx = (gx + 50.0f) / 0.5f;   // lo_x = -50 exact; /0.5 exact
    float ty = (gy + 50.0f) / 0.5f;
    float tz = (gz + 10.0f) / 20.0f;  // correctly-rounded IEEE f32 division

    int ix = (int)tx;  // trunc toward zero == numpy astype(int32); (-1,0) -> 0 kept
    int iy = (int)ty;
    int iz = (int)tz;

    if (!((ix >= 0) && (ix < 200) && (iy >= 0) && (iy < 200) && (iz == 0))) return;

    float* dst = acc + (size_t)(ix * 200 + iy) * cg;
    const float* row = x + (size_t)p * NCH + c0;

    int k4 = cg >> 2;                       // cg is a power of 2
    const float4* rv = (const float4*)row;  // 16B-aligned (c0 multiple of cg >= 4)
    for (int k = 0; k < k4; ++k) {
        float4 v = rv[k];
        atomic_add_agent(dst + 4 * k + 0, v.x);
        atomic_add_agent(dst + 4 * k + 1, v.y);
        atomic_add_agent(dst + 4 * k + 2, v.z);
        atomic_add_agent(dst + 4 * k + 3, v.w);
    }
    for (int k = k4 << 2; k < cg; ++k)      // cg in {1,2} fallback
        atomic_add_agent(dst + k, row[k]);
}

// acc is (voxel, cg) for channel group [c0, c0+cg); out is (C, 200, 200) f32.
__global__ void __launch_bounds__(256)
lss_finalize(const float* __restrict__ acc, float* __restrict__ out,
             int c0, int cg) {
    int t = blockIdx.x * blockDim.x + threadIdx.x;
    if (t >= NVOX * cg) return;
    int cl = t / NVOX;      // local channel within group
    int s  = t - cl * NVOX; // voxel = ix*200+iy
    out[(size_t)(c0 + cl) * NVOX + s] = acc[(size_t)s * cg + cl];
}

extern "C" void kernel_launch(void* const* d_in, const int* in_sizes, int n_in,
                              void* d_out, int out_size, void* d_ws, size_t ws_size,
                              hipStream_t stream) {
    const float* geom = (const float*)d_in[0];
    const float* x    = (const float*)d_in[1];
    int gsz = in_sizes[0], xsz = in_sizes[1];
    if (gsz > xsz) {  // defensive: geom (nprime*3) is the smaller input
        const float* tmp = geom; geom = x; x = tmp;
        int t2 = gsz; gsz = xsz; xsz = t2;
    }
    float* acc = (float*)d_ws;
    float* out = (float*)d_out;

    int nprime = xsz / NCH;  // 2,770,944

    // Largest power-of-2 channel group whose f32 accumulator fits in ws.
    int cg = NCH;
    while (cg > 1 && (size_t)NVOX * cg * sizeof(float) > ws_size) cg >>= 1;

    int threads = 256;
    int blocks_scatter = (nprime + threads - 1) / threads;

    for (int c0 = 0; c0 < NCH; c0 += cg) {
        hipMemsetAsync(acc, 0, (size_t)NVOX * cg * sizeof(float), stream);
        lss_scatter<<<blocks_scatter, threads, 0, stream>>>(geom, x, acc, nprime, c0, cg);
        int total = NVOX * cg;
        lss_finalize<<<(total + threads - 1) / threads, threads, 0, stream>>>(acc, out, c0, cg);
    }
}